// Round 3
// baseline (1965.870 us; speedup 1.0000x reference)
//
#include <hip/hip_runtime.h>
#include <math.h>

// Problem constants (fixed by setup_inputs)
constexpr int B_   = 8;
constexpr int CIN  = 64;     // dim
constexpr int C3   = 192;    // 3*dim
constexpr int HWID = 256;
constexpr long long NPIX = 65536; // 256*256

// Per-batch workspace layout (floats) — total ~21M floats (~84 MB)
constexpr size_t SZ_QKV1B = (size_t)C3 * NPIX;         // [192][65536] 1x1 out, one batch
constexpr size_t SZ_QKB   = (size_t)128 * NPIX;        // [128][65536] dw q,k one batch
constexpr size_t OFF_QKV1B = 0;
constexpr size_t OFF_QKB   = OFF_QKV1B + SZ_QKV1B;
constexpr size_t OFF_GRAM  = OFF_QKB + SZ_QKB;         // [8][2][32][32]
constexpr size_t SZ_GRAM   = (size_t)B_ * 2 * 32 * 32;
constexpr size_t OFF_NORM  = OFF_GRAM + SZ_GRAM;       // [8][2][64]
constexpr size_t SZ_NORM   = (size_t)B_ * 2 * 64;
constexpr size_t OFF_M     = OFF_NORM + SZ_NORM;       // [8][64][64]
constexpr size_t SZ_M      = (size_t)B_ * 64 * 64;

// ---------------------------------------------------------------------------
// K1: qkv1 = W_qkv (192x64) @ x_b (64xN), one batch.  Thread = pixel.
// grid (256, 2): blockIdx.y picks a 96-wide oc group.  oc unrolled x4 for
// independent FMA chains.
// ---------------------------------------------------------------------------
__global__ __launch_bounds__(256) void k1_qkv1x1(const float* __restrict__ x,
                                                 const float* __restrict__ wqkv,
                                                 float* __restrict__ qkv1, int b) {
  const int ocg = blockIdx.y;
  const long long n = (long long)blockIdx.x * 256 + threadIdx.x;
  const float* xb = x + (size_t)b * CIN * NPIX + n;
  float xr[64];
#pragma unroll
  for (int ic = 0; ic < 64; ++ic) xr[ic] = xb[(size_t)ic * NPIX];
  float* outb = qkv1 + n;
  const int oc0 = ocg * 96, oc1 = oc0 + 96;
  for (int oc = oc0; oc < oc1; oc += 4) {
    const float* w0 = wqkv + oc * 64;
    float a0 = 0.f, a1 = 0.f, a2 = 0.f, a3 = 0.f;
#pragma unroll
    for (int ic = 0; ic < 64; ++ic) {
      const float xv = xr[ic];
      a0 = fmaf(w0[ic], xv, a0);
      a1 = fmaf(w0[64 + ic], xv, a1);
      a2 = fmaf(w0[128 + ic], xv, a2);
      a3 = fmaf(w0[192 + ic], xv, a3);
    }
    outb[(size_t)oc * NPIX] = a0;
    outb[(size_t)(oc + 1) * NPIX] = a1;
    outb[(size_t)(oc + 2) * NPIX] = a2;
    outb[(size_t)(oc + 3) * NPIX] = a3;
  }
}

// ---------------------------------------------------------------------------
// K2: depthwise 3x3 pad 1, one batch.  Block = (row, ch); threads = cols.
// q,k channels (ch<128) -> qkbuf; v channels (ch>=128) -> d_out[b] directly.
// ---------------------------------------------------------------------------
__global__ __launch_bounds__(256) void k2_dwconv(const float* __restrict__ qkv1,
                                                 const float* __restrict__ wdw,
                                                 float* __restrict__ qkbuf,
                                                 float* __restrict__ vout) {
  const int row = blockIdx.x;
  const int ch  = blockIdx.y;
  const int col = threadIdx.x;
  const float* p = qkv1 + (size_t)ch * NPIX;
  float w[9];
#pragma unroll
  for (int i = 0; i < 9; ++i) w[i] = wdw[ch * 9 + i];
  float acc = 0.f;
#pragma unroll
  for (int dy = -1; dy <= 1; ++dy) {
    const int r = row + dy;
    if (r >= 0 && r < HWID) {
#pragma unroll
      for (int dx = -1; dx <= 1; ++dx) {
        const int c = col + dx;
        if (c >= 0 && c < HWID)
          acc = fmaf(w[(dy + 1) * 3 + (dx + 1)], p[(size_t)r * HWID + c], acc);
      }
    }
  }
  float* dst = (ch < 128) ? (qkbuf + (size_t)ch * NPIX)
                          : (vout + (size_t)(ch - 128) * NPIX);
  dst[(size_t)row * HWID + col] = acc;
}

// ---------------------------------------------------------------------------
// K3: Gram G[b,h][c][d] = sum_n q[c][n]*k[d][n] (+ squared norms), one batch.
// qkbuf: q = ch 0..63, k = ch 64..127.  grid (32 n-chunks, 2 heads).
// Thread t: nt = t&15 n-lane; tile = t>>4 -> 8x8 (c,d) register tile.
// ---------------------------------------------------------------------------
__global__ __launch_bounds__(256) void k3_gram(const float* __restrict__ qkbuf,
                                               float* __restrict__ gram,
                                               float* __restrict__ norms, int b) {
  const int chunk = blockIdx.x;   // 0..31
  const int h = blockIdx.y;       // 0..1
  const int t = threadIdx.x;
  const int nt = t & 15;
  const int tile = t >> 4;        // 0..15
  const int c0 = (tile & 3) * 8;
  const int d0 = (tile >> 2) * 8;
  const float* qb = qkbuf + (size_t)(h * 32) * NPIX;
  const float* kb = qkbuf + (size_t)(64 + h * 32) * NPIX;

  float acc[8][8];
#pragma unroll
  for (int i = 0; i < 8; ++i)
#pragma unroll
    for (int j = 0; j < 8; ++j) acc[i][j] = 0.f;
  float qn[8], kn[8];
#pragma unroll
  for (int i = 0; i < 8; ++i) { qn[i] = 0.f; kn[i] = 0.f; }

  const long long n0 = (long long)chunk * 2048 + nt;
  for (int s = 0; s < 128; ++s) {
    const long long n = n0 + s * 16;
    float qv[8], kv[8];
#pragma unroll
    for (int i = 0; i < 8; ++i) qv[i] = qb[(size_t)(c0 + i) * NPIX + n];
#pragma unroll
    for (int j = 0; j < 8; ++j) kv[j] = kb[(size_t)(d0 + j) * NPIX + n];
#pragma unroll
    for (int i = 0; i < 8; ++i)
#pragma unroll
      for (int j = 0; j < 8; ++j) acc[i][j] = fmaf(qv[i], kv[j], acc[i][j]);
    if (d0 == 0) {  // tile-uniform within each 16-lane shfl group
#pragma unroll
      for (int i = 0; i < 8; ++i) qn[i] = fmaf(qv[i], qv[i], qn[i]);
    }
    if (c0 == 0) {
#pragma unroll
      for (int j = 0; j < 8; ++j) kn[j] = fmaf(kv[j], kv[j], kn[j]);
    }
  }

  float* gb = gram + (((size_t)b * 2 + h) * 32) * 32;
#pragma unroll
  for (int i = 0; i < 8; ++i)
#pragma unroll
    for (int j = 0; j < 8; ++j) {
      float v = acc[i][j];
      v += __shfl_xor(v, 1);
      v += __shfl_xor(v, 2);
      v += __shfl_xor(v, 4);
      v += __shfl_xor(v, 8);
      if (nt == 0) atomicAdd(&gb[(c0 + i) * 32 + (d0 + j)], v);
    }
  float* nb = norms + ((size_t)b * 2 + h) * 64;
  if (d0 == 0) {
#pragma unroll
    for (int i = 0; i < 8; ++i) {
      float v = qn[i];
      v += __shfl_xor(v, 1); v += __shfl_xor(v, 2);
      v += __shfl_xor(v, 4); v += __shfl_xor(v, 8);
      if (nt == 0) atomicAdd(&nb[c0 + i], v);
    }
  }
  if (c0 == 0) {
#pragma unroll
    for (int j = 0; j < 8; ++j) {
      float v = kn[j];
      v += __shfl_xor(v, 1); v += __shfl_xor(v, 2);
      v += __shfl_xor(v, 4); v += __shfl_xor(v, 8);
      // channel index is d0 + j (BUGFIX R2: was nb[32 + j] — collapsed all
      // k-norm tiles onto channels 0..7, left 8..31 zero)
      if (nt == 0) atomicAdd(&nb[32 + d0 + j], v);
    }
  }
}

// ---------------------------------------------------------------------------
// K4: all batches.  Normalize gram -> attn; rank-based top-k (16,21,24)
// masked softmaxes; A = a1*sm1+a2*sm2+a3*sm3; fold with W_proj -> M (64x64).
// grid(8), block 256; threads <64 own one attention row each.
// ---------------------------------------------------------------------------
__global__ __launch_bounds__(256) void k4_attn(const float* __restrict__ gram,
                                               const float* __restrict__ norms,
                                               const float* __restrict__ temp,
                                               const float* __restrict__ a1,
                                               const float* __restrict__ a2,
                                               const float* __restrict__ a3,
                                               const float* __restrict__ wproj,
                                               float* __restrict__ M) {
  const int b = blockIdx.x;
  const int t = threadIdx.x;
  __shared__ float A[2][32][32];
  if (t < 64) {
    const int h = t >> 5, c = t & 31;
    const float* g = gram + (((size_t)b * 2 + h) * 32 + c) * 32;
    const float* nb = norms + ((size_t)b * 2 + h) * 64;
    const float qn = fmaxf(sqrtf(nb[c]), 1e-12f);
    const float tmph = temp[h];
    float v[32];
#pragma unroll
    for (int d = 0; d < 32; ++d) {
      const float kn = fmaxf(sqrtf(nb[32 + d]), 1e-12f);
      v[d] = g[d] / (qn * kn) * tmph;
    }
    // rank(i) = #{j : v_j > v_i or (v_j == v_i and j < i)} matches top_k ties
    int rank[32];
#pragma unroll
    for (int i = 0; i < 32; ++i) {
      int r = 0;
#pragma unroll
      for (int j = 0; j < 32; ++j)
        r += (v[j] > v[i]) || (v[j] == v[i] && j < i);
      rank[i] = r;
    }
    float acc[32];
#pragma unroll
    for (int d = 0; d < 32; ++d) acc[d] = 0.f;
    const float aws[3] = {a1[0], a2[0], a3[0]};
    const int kvs[3] = {16, 21, 24};  // C/2, 2C/3, 3C/4 for C=32
#pragma unroll 1
    for (int kk = 0; kk < 3; ++kk) {
      float mx = -3.4e38f;
#pragma unroll
      for (int d = 0; d < 32; ++d)
        if (rank[d] < kvs[kk]) mx = fmaxf(mx, v[d]);
      float s = 0.f;
#pragma unroll
      for (int d = 0; d < 32; ++d)
        if (rank[d] < kvs[kk]) s += expf(v[d] - mx);
      const float inv = aws[kk] / s;
#pragma unroll
      for (int d = 0; d < 32; ++d)
        if (rank[d] < kvs[kk]) acc[d] += expf(v[d] - mx) * inv;
    }
#pragma unroll
    for (int d = 0; d < 32; ++d) A[h][c][d] = acc[d];
  }
  __syncthreads();
  // M[oc][h*32+d] = sum_c Wp[oc][h*32+c] * A[h][c][d]
  for (int e = t; e < 4096; e += 256) {
    const int oc = e >> 6, j = e & 63, h = j >> 5, d = j & 31;
    float s = 0.f;
#pragma unroll
    for (int c = 0; c < 32; ++c)
      s += wproj[oc * 64 + h * 32 + c] * A[h][c][d];
    M[(size_t)b * 4096 + e] = s;
  }
}

// ---------------------------------------------------------------------------
// K5: y[b] = M[b] (64x64) @ v[b] (64xN), all batches.  v lives in d_out and
// is overwritten IN PLACE: each thread owns one pixel column — loads all 64
// v values into registers, then stores all 64 outputs.
// ---------------------------------------------------------------------------
__global__ __launch_bounds__(256) void k5_out(float* vy,
                                              const float* __restrict__ M) {
  const int b = blockIdx.y;
  const long long n = (long long)blockIdx.x * 256 + threadIdx.x;
  float* vb = vy + (size_t)b * 64 * NPIX + n;
  float vr[64];
#pragma unroll
  for (int j = 0; j < 64; ++j) vr[j] = vb[(size_t)j * NPIX];
  const float* Mb = M + (size_t)b * 4096;
  for (int oc = 0; oc < 64; ++oc) {
    const float* wrow = Mb + oc * 64;
    float a0 = 0.f, a1 = 0.f;
#pragma unroll
    for (int j = 0; j < 32; ++j) {
      a0 = fmaf(wrow[j], vr[j], a0);
      a1 = fmaf(wrow[32 + j], vr[32 + j], a1);
    }
    vb[(size_t)oc * NPIX] = a0 + a1;
  }
}

extern "C" void kernel_launch(void* const* d_in, const int* in_sizes, int n_in,
                              void* d_out, int out_size, void* d_ws, size_t ws_size,
                              hipStream_t stream) {
  const float* x     = (const float*)d_in[0];
  const float* wqkv  = (const float*)d_in[1];
  const float* wdw   = (const float*)d_in[2];
  const float* wproj = (const float*)d_in[3];
  const float* temp  = (const float*)d_in[4];
  const float* a1    = (const float*)d_in[5];
  const float* a2    = (const float*)d_in[6];
  const float* a3    = (const float*)d_in[7];

  float* ws    = (float*)d_ws;
  float* qkv1b = ws + OFF_QKV1B;
  float* qkb   = ws + OFF_QKB;
  float* gram  = ws + OFF_GRAM;
  float* norms = ws + OFF_NORM;
  float* M     = ws + OFF_M;
  float* y     = (float*)d_out;

  // zero the atomic accumulators (gram + norms contiguous)
  hipMemsetAsync(gram, 0, (SZ_GRAM + SZ_NORM) * sizeof(float), stream);

  dim3 blk(256);
  for (int b = 0; b < B_; ++b) {
    k1_qkv1x1<<<dim3(256, 2), blk, 0, stream>>>(x, wqkv, qkv1b, b);
    k2_dwconv<<<dim3(HWID, C3), blk, 0, stream>>>(
        qkv1b, wdw, qkb, y + (size_t)b * 64 * NPIX);
    k3_gram<<<dim3(32, 2), blk, 0, stream>>>(qkb, gram, norms, b);
  }
  k4_attn<<<dim3(B_), blk, 0, stream>>>(gram, norms, temp, a1, a2, a3, wproj, M);
  k5_out<<<dim3(256, B_), blk, 0, stream>>>(y, M);
}